// Round 8
// baseline (156.602 us; speedup 1.0000x reference)
//
#include <hip/hip_runtime.h>

// Problem constants
#define BB 256
#define PP 128
#define KK 16
#define HH 128
#define OO 256
#define EE 18      // 2*(C+F)
#define XCH 10     // C + F + 1 (coords, feats, mask)
#define BIGD 1000000000.0f
#define NPB 8      // points per block = 2 groups of 4 (4 waves, 2 pipeline stages)
#define XS 11      // LDS row stride for staged x (odd -> bank spread)

typedef __bf16 bf16x8 __attribute__((ext_vector_type(8)));
typedef __bf16 bf16x4 __attribute__((ext_vector_type(4)));
typedef float  f32x4  __attribute__((ext_vector_type(4)));

// ---------------------------------------------------------------------------
// Kernel 1: pack W2 and W1 into bf16 MFMA fragment order.
// W2p (B-frag, 16x16x32): [ct 16][ks 4][lane 64][j 8], elem = W2[ks*32+(l>>4)*8+j][ct*16+(l&15)]
// W1p (A-frag for h1^T = W1^T @ edge^T): [nt 8][lane 64][j 8],
//   elem = W1[k][nt*16+(l&15)] for k=(l>>4)*8+j < 18, else 0 (K padded to 32).
// ---------------------------------------------------------------------------
__global__ __launch_bounds__(256) void pack_w_kernel(const float* __restrict__ W1,
                                                     const float* __restrict__ W2,
                                                     __bf16* __restrict__ W2p,
                                                     __bf16* __restrict__ W1p) {
    const int t = blockIdx.x * 256 + threadIdx.x;  // 0 .. 36863
    if (t < 32768) {
        const int j  = t & 7;
        const int l  = (t >> 3) & 63;
        const int ks = (t >> 9) & 3;
        const int ct = t >> 11;
        const int row = ks * 32 + ((l >> 4) * 8) + j;
        const int col = ct * 16 + (l & 15);
        W2p[t] = (__bf16)W2[row * OO + col];
    } else {
        const int t2 = t - 32768;  // 0 .. 4095
        const int j  = t2 & 7;
        const int l  = (t2 >> 3) & 63;
        const int nt = t2 >> 9;
        const int k  = ((l >> 4) * 8) + j;
        const int n  = nt * 16 + (l & 15);
        W1p[t2] = (k < EE) ? (__bf16)W1[k * HH + n] : (__bf16)0.0f;
    }
}

// ---------------------------------------------------------------------------
// Kernel 2: fully-fused EdgeConv, software-pipelined over 2 point-groups.
// One block = 8 points = 2 groups x 4 points; 4 waves; wave w owns point w of
// each group and output col-tiles {4w..4w+3}.
// Pipeline (per wave):  prefetch bfr/b2 | stage x | BAR |
//   knn0 -> GEMM1_0 -> buf0 | BAR | issue GEMM2_0 (64 MFMA in flight)
//   -> knn1 + GEMM1_1 -> buf1  (SALU/VALU overlap the MFMA shadow)
//   -> epilogue_0 (waits acc) | BAR | GEMM2_1 -> epilogue_1.
// The radix select (~400 SALU-cyc on the CU-shared scalar unit) thus runs
// under group-0's MFMA instead of serially on the critical path.
// knn: key = (d_bits<<7)|j, unique; ascending == lexicographic (d,j) ==
// jax.lax.top_k stable order; self = unique d=0 min = the dropped nearest.
// dist2 via __fmul_rn/__fadd_rn matches numpy bit-exact.
// ---------------------------------------------------------------------------
__global__ __launch_bounds__(256, 2) void mlp_kernel(const float* __restrict__ x,
                                                     const __bf16* __restrict__ W1p,
                                                     const float* __restrict__ b1,
                                                     const __bf16* __restrict__ W2p,
                                                     const float* __restrict__ b2,
                                                     float* __restrict__ out) {
    __shared__ float  sxr[PP * XS];          // staged x rows, stride 11: 5632 B
    __shared__ __bf16 sh1A[2][16 * 64 * 8];  // double-buffered h1 A-frags, 32 KB
    __shared__ int    sknn[4][KK];           // per-wave winner slots

    const int tid = threadIdx.x;
    const int lane = tid & 63;
    const int w = tid >> 6;        // wave id
    const int quad = lane >> 4;
    const int lcol = lane & 15;

    const int pbase = blockIdx.x * NPB;
    const int bidx = pbase >> 7;
    const int i0 = pbase & (PP - 1);
    const float* xb = x + (size_t)bidx * PP * XCH;
    float* outrow = out + (size_t)pbase * (OO + 1);

    // ---- prefetch: GEMM2 B-frags (reused by BOTH groups) + b2 columns ----
    bf16x8 bfr[4][4];
#pragma unroll
    for (int ks = 0; ks < 4; ++ks)
#pragma unroll
        for (int ct = 0; ct < 4; ++ct)
            bfr[ks][ct] = *(const bf16x8*)&W2p[(size_t)((((w * 4 + ct) * 4 + ks) * 64 + lane) * 8)];
    float bc[4];
#pragma unroll
    for (int ct = 0; ct < 4; ++ct) bc[ct] = b2[w * 64 + ct * 16 + lcol];

    // ---- masks + early-exit (8-point block fully masked: mask is a prefix) --
    bool anylive = false;
#pragma unroll
    for (int g = 0; g < NPB; ++g) anylive |= (xb[(i0 + g) * XCH + 9] != 0.0f);
    if (!anylive) {
        // out is re-poisoned before every launch: must write zeros
        for (int o = tid; o < NPB * (OO + 1); o += 256) outrow[o] = 0.0f;
        return;  // uniform exit, no barrier mismatch
    }

    // ---- stage batch x into LDS (coalesced, 5 dwords/thread) ----
    for (int t = tid; t < PP * XCH; t += 256) {
        const int r = t / XCH;
        const int c = t - r * XCH;
        sxr[r * XS + c] = xb[t];
    }
    __syncthreads();   // BAR A

    // ======================= per-wave building blocks ======================
    auto knn_select = [&](int ip) {
        if (sxr[ip * XS + 9] != 0.0f) {   // wave-uniform
            const float cix = sxr[ip * XS + 0];
            const float ciy = sxr[ip * XS + 1];
            const int j0 = lane, j1 = lane + 64;
            float d0, d1;
            {
                const float mj = sxr[j0 * XS + 9];
                const float dx = cix - sxr[j0 * XS + 0];
                const float dy = ciy - sxr[j0 * XS + 1];
                d0 = __fadd_rn(__fmul_rn(dx, dx), __fmul_rn(dy, dy));
                if (mj <= 0.0f || j0 == ip) d0 = BIGD;
            }
            {
                const float mj = sxr[j1 * XS + 9];
                const float dx = cix - sxr[j1 * XS + 0];
                const float dy = ciy - sxr[j1 * XS + 1];
                d1 = __fadd_rn(__fmul_rn(dx, dx), __fmul_rn(dy, dy));
                if (mj <= 0.0f || j1 == ip) d1 = BIGD;
            }
            const unsigned d0b = __float_as_uint(d0);
            const unsigned d1b = __float_as_uint(d1);

            unsigned long long A0 = ~0ull, A1 = ~0ull, W0 = 0ull, W1 = 0ull;
            int need = KK;
            auto step = [&](unsigned long long q0, unsigned long long q1) {
                const unsigned long long z0 = A0 & q0;
                const unsigned long long z1 = A1 & q1;
                const int c = __popcll(z0) + __popcll(z1);
                if (c == need) { W0 |= z0; W1 |= z1; A0 = A1 = 0ull; need = 0; }
                else if (c > need) { A0 = z0; A1 = z1; }
                else { W0 |= z0; W1 |= z1; need -= c; A0 &= ~z0; A1 &= ~z1; }
            };
#pragma unroll 1
            for (int bp = 30; bp >= 0; --bp) {   // bit 31 = sign = always 0
                if (need == 0) break;
                const unsigned long long q0 = __ballot(((d0b >> bp) & 1u) == 0u);
                const unsigned long long q1 = __ballot(((d1b >> bp) & 1u) == 0u);
                step(q0, q1);
            }
            if (need) step(~0ull, 0ull);  // index bit 6: all j0=0, all j1=1
            {
                const unsigned long long M5 = 0x00000000FFFFFFFFull;
                const unsigned long long M4 = 0x0000FFFF0000FFFFull;
                const unsigned long long M3 = 0x00FF00FF00FF00FFull;
                const unsigned long long M2 = 0x0F0F0F0F0F0F0F0Full;
                const unsigned long long M1 = 0x3333333333333333ull;
                const unsigned long long M0 = 0x5555555555555555ull;
                if (need) step(M5, M5);
                if (need) step(M4, M4);
                if (need) step(M3, M3);
                if (need) step(M2, M2);
                if (need) step(M1, M1);
                if (need) step(M0, M0);
            }
            W0 |= A0; W1 |= A1;  // keys unique => remaining actives = the rest

            unsigned int mb0 = __builtin_amdgcn_mbcnt_lo((unsigned)(W0 & 0xffffffffull), 0u);
            mb0 = __builtin_amdgcn_mbcnt_hi((unsigned)(W0 >> 32), mb0);
            unsigned int mb1 = __builtin_amdgcn_mbcnt_lo((unsigned)(W1 & 0xffffffffull), 0u);
            mb1 = __builtin_amdgcn_mbcnt_hi((unsigned)(W1 >> 32), mb1);
            const int base1 = __popcll(W0);
            if ((W0 >> lane) & 1ull) sknn[w][mb0] = j0;
            if ((W1 >> lane) & 1ull) sknn[w][base1 + mb1] = j1;
        } else {
            if (lane < KK) sknn[w][lane] = 0;  // dummy (output row masked to 0)
        }
    };

    // edge build -> GEMM1 B-fragment: neighbor slot lcol, channels quad*8..+7
    auto build_ef = [&](int ip) -> bf16x8 {
        const int jn = sknn[w][lcol];          // intra-wave LDS dep, no barrier
        bf16x8 ef;
#pragma unroll
        for (int e = 0; e < 8; ++e) {
            const int c = quad * 8 + e;                         // 0..31
            const int cA = (c < 9) ? c : ((c < 18) ? c - 9 : 0);
            const int cN = (c >= 9 && c < 18) ? c - 9 : 0;
            const float rA = sxr[ip * XS + cA];
            const float rN = sxr[jn * XS + cN];
            float vv = (c < 9) ? rA : (rN - rA);
            if (c >= 18) vv = 0.0f;                             // K pad 18 -> 32
            ef[e] = (__bf16)vv;
        }
        return ef;
    };

    const f32x4 z4 = {0.0f, 0.0f, 0.0f, 0.0f};

    // GEMM1 (8 MFMA) + relu(+b1) -> bf16 A-frag-order write into buffer sbuf
    auto gemm1_to = [&](int sbuf, bf16x8 ef) {
        bf16x8 wf[8];
#pragma unroll
        for (int nt = 0; nt < 8; ++nt)
            wf[nt] = *(const bf16x8*)&W1p[(size_t)((nt * 64 + lane) * 8)];
        f32x4 h[8];
#pragma unroll
        for (int nt = 0; nt < 8; ++nt)
            h[nt] = __builtin_amdgcn_mfma_f32_16x16x32_bf16(wf[nt], ef, z4, 0, 0, 0);
#pragma unroll
        for (int nt = 0; nt < 8; ++nt) {
            const f32x4 bv = *(const f32x4*)&b1[nt * 16 + quad * 4];  // L1-hot
            const int ks = nt >> 1;
            const int lp = (((nt * 2 + (quad >> 1)) & 3) << 4) | lcol;
            bf16x4 hv;
#pragma unroll
            for (int r = 0; r < 4; ++r)
                hv[r] = (__bf16)fmaxf(h[nt][r] + bv[r], 0.0f);
            *(bf16x4*)&sh1A[sbuf][((ks * 4 + w) * 64 + lp) * 8 + (quad & 1) * 4] = hv;
        }
    };

    // GEMM2 issue: 64 MFMA into acc (results consumed later -> MFMA shadow)
    auto gemm2_issue = [&](int sbuf, f32x4 (&acc)[4][4]) {
#pragma unroll
        for (int g = 0; g < 4; ++g)
#pragma unroll
            for (int ct = 0; ct < 4; ++ct) acc[g][ct] = z4;
#pragma unroll
        for (int ks = 0; ks < 4; ++ks) {
            bf16x8 af[4];
#pragma unroll
            for (int g = 0; g < 4; ++g)
                af[g] = *(const bf16x8*)&sh1A[sbuf][((ks * 4 + g) * 64 + lane) * 8];
#pragma unroll
            for (int g = 0; g < 4; ++g)
#pragma unroll
                for (int ct = 0; ct < 4; ++ct)
                    acc[g][ct] = __builtin_amdgcn_mfma_f32_16x16x32_bf16(
                        af[g], bfr[ks][ct], acc[g][ct], 0, 0, 0);
        }
    };

    // epilogue: relu(+b2), K-sum = tile column-sum via shfl, masked store
    auto epi2_store = [&](f32x4 (&acc)[4][4], int gb) {
        float val[4];
#pragma unroll
        for (int g = 0; g < 4; ++g) {
#pragma unroll
            for (int ct = 0; ct < 4; ++ct) {
                float s = 0.0f;
#pragma unroll
                for (int r = 0; r < 4; ++r) s += fmaxf(acc[g][ct][r] + bc[ct], 0.0f);
                s += __shfl_xor(s, 16, 64);
                s += __shfl_xor(s, 32, 64);
                if (quad == g) val[ct] = s;   // lane (quad=g, lcol) keeps point g
            }
        }
        const float msc = sxr[(i0 + gb + quad) * XS + 9] * (1.0f / KK);
#pragma unroll
        for (int ct = 0; ct < 4; ++ct)
            outrow[(size_t)(gb + quad) * (OO + 1) + w * 64 + ct * 16 + lcol] = val[ct] * msc;
    };

    // ============================ pipeline =================================
    const int ip0 = i0 + w;        // group-0 point of this wave
    const int ip1 = i0 + 4 + w;    // group-1 point

    knn_select(ip0);
    gemm1_to(0, build_ef(ip0));
    __syncthreads();   // BAR B: buf0 ready

    f32x4 acc0[4][4];
    gemm2_issue(0, acc0);          // 64 MFMA in flight
    knn_select(ip1);               // SALU select overlaps MFMA shadow
    gemm1_to(1, build_ef(ip1));
    epi2_store(acc0, 0);           // waits on acc0, stores group 0
    __syncthreads();   // BAR C: buf1 ready

    f32x4 acc1[4][4];
    gemm2_issue(1, acc1);
    epi2_store(acc1, 4);

    // ones channel * mask
    if (tid < NPB) outrow[(size_t)tid * (OO + 1) + OO] = sxr[(i0 + tid) * XS + 9];
}

extern "C" void kernel_launch(void* const* d_in, const int* in_sizes, int n_in,
                              void* d_out, int out_size, void* d_ws, size_t ws_size,
                              hipStream_t stream) {
    const float* x  = (const float*)d_in[0];
    const float* W1 = (const float*)d_in[1];
    const float* b1 = (const float*)d_in[2];
    const float* W2 = (const float*)d_in[3];
    const float* b2 = (const float*)d_in[4];
    float* out = (float*)d_out;

    __bf16* W2p = (__bf16*)d_ws;                    // 64 KB
    __bf16* W1p = (__bf16*)((char*)d_ws + 65536);   // 8 KB

    pack_w_kernel<<<144, 256, 0, stream>>>(W1, W2, W2p, W1p);

    const int nblocks = (BB * PP) / NPB;  // 4096
    mlp_kernel<<<nblocks, 256, 0, stream>>>(x, W1p, b1, W2p, b2, out);
}

// Round 9
// 128.689 us; speedup vs baseline: 1.2169x; 1.2169x over previous
//
#include <hip/hip_runtime.h>

// Problem constants
#define BB 256
#define PP 128
#define KK 16
#define HH 128
#define OO 256
#define EE 18      // 2*(C+F)
#define XCH 10     // C + F + 1 (coords, feats, mask)
#define BIGD 1000000000.0f
#define GPT 4      // points per block (= waves per block)

typedef __bf16 bf16x8 __attribute__((ext_vector_type(8)));
typedef __bf16 bf16x4 __attribute__((ext_vector_type(4)));
typedef float  f32x4  __attribute__((ext_vector_type(4)));

// ---------------------------------------------------------------------------
// Kernel 1: pack W2 and W1 into bf16 MFMA fragment order.
// W2p (B-frag, 16x16x32): [ct 16][ks 4][lane 64][j 8], elem = W2[ks*32+(l>>4)*8+j][ct*16+(l&15)]
// W1p (A-frag for h1^T = W1^T @ edge^T): [nt 8][lane 64][j 8],
//   elem = W1[k][nt*16+(l&15)] for k=(l>>4)*8+j < 18, else 0 (K padded to 32).
// ---------------------------------------------------------------------------
__global__ __launch_bounds__(256) void pack_w_kernel(const float* __restrict__ W1,
                                                     const float* __restrict__ W2,
                                                     __bf16* __restrict__ W2p,
                                                     __bf16* __restrict__ W1p) {
    const int t = blockIdx.x * 256 + threadIdx.x;  // 0 .. 36863
    if (t < 32768) {
        const int j  = t & 7;
        const int l  = (t >> 3) & 63;
        const int ks = (t >> 9) & 3;
        const int ct = t >> 11;
        const int row = ks * 32 + ((l >> 4) * 8) + j;
        const int col = ct * 16 + (l & 15);
        W2p[t] = (__bf16)W2[row * OO + col];
    } else {
        const int t2 = t - 32768;  // 0 .. 4095
        const int j  = t2 & 7;
        const int l  = (t2 >> 3) & 63;
        const int nt = t2 >> 9;
        const int k  = ((l >> 4) * 8) + j;
        const int n  = nt * 16 + (l & 15);
        W1p[t2] = (k < EE) ? (__bf16)W1[k * HH + n] : (__bf16)0.0f;
    }
}

// ---------------------------------------------------------------------------
// Kernel 2: fully-fused EdgeConv: per-block KNN + edge-MLP (all-MFMA).
// One block = 4 points = 4 waves (r5 structure — best measured).
//
//  - KNN (wave w, point w): RADIX-4 select over 128 candidates (lane l owns
//    j=l and j=l+64). key = (d_bits << 7) | j : unique, ascending key order
//    == lexicographic (d, j) == jax.lax.top_k's stable order (d >= 0 so fp32
//    bits are monotone as uint). Self is the unique d=0 min == the dropped
//    "nearest", so exclude it and select the top-16 SET (slot order matches
//    r5's compaction -> identical sums). Radix-4 halves the serial
//    ballot->popc->select chain vs radix-2 (16 rounds vs 38); |A|==need
//    fast-exit terminates typically within ~8-12 rounds.
//    dist2 uses __fmul_rn/__fadd_rn to match numpy bit-exact.
//  - Edge build: thread (w*64+l) computes exactly the GEMM1 B-fragment lane
//    l of tile w needs -> edges live only in registers.
//  - GEMM1 (MFMA): h1^T tiles = W1p-frag x edge-frag; relu+bias; bf16 b64
//    writes into sh1A in GEMM2 A-frag order (2-way banks = free).
//  - GEMM2 (MFMA): 64 MFMA/wave; epilogue relu+bias, tile-column sum = K-sum
//    via shfl_xor(16/32); coalesced stores. 3 barriers total.
// ---------------------------------------------------------------------------
__global__ __launch_bounds__(256, 4) void mlp_kernel(const float* __restrict__ x,
                                                     const __bf16* __restrict__ W1p,
                                                     const float* __restrict__ b1,
                                                     const __bf16* __restrict__ W2p,
                                                     const float* __restrict__ b2,
                                                     float* __restrict__ out) {
    __shared__ __bf16 sh1A[16 * 64 * 8];  // [ks*4+g][lane][j], 16 KB
    __shared__ float  sb1[HH];
    __shared__ float  sb2[OO];
    __shared__ float  smask[GPT];
    __shared__ int    sknn[GPT][KK];      // per-wave winner slots

    const int tid = threadIdx.x;
    const int lane = tid & 63;
    const int w = tid >> 6;
    const int quad = lane >> 4;
    const int lcol = lane & 15;

    const int pbase = blockIdx.x * GPT;
    const int bidx = pbase >> 7;
    const int i0 = pbase & (PP - 1);
    const float* xb = x + (size_t)bidx * PP * XCH;
    float* outrow = out + (size_t)pbase * (OO + 1);

    if (tid < HH) sb1[tid] = b1[tid];
    sb2[tid] = b2[tid];
    if (tid < GPT) smask[tid] = xb[(i0 + tid) * XCH + (XCH - 1)];
    __syncthreads();

    const bool allmasked =
        (smask[0] == 0.0f) & (smask[1] == 0.0f) & (smask[2] == 0.0f) & (smask[3] == 0.0f);
    if (allmasked) {
        // out is re-poisoned before every launch: must write zeros
        for (int o = tid; o < GPT * (OO + 1); o += 256) outrow[o] = 0.0f;
        return;  // uniform: all threads exit, no barrier mismatch
    }

    // ================= KNN: wave w selects 16 neighbors of point i0+w ======
    const int i = i0 + w;
    if (smask[w] != 0.0f) {   // wave-uniform
        const float cix = xb[i * XCH + 0];
        const float ciy = xb[i * XCH + 1];

        const int j0 = lane, j1 = lane + 64;
        float d0, d1;
        {
            const float2 c0 = *(const float2*)(xb + j0 * XCH);
            const float m0 = xb[j0 * XCH + (XCH - 1)];
            float dx = cix - c0.x, dy = ciy - c0.y;
            d0 = __fadd_rn(__fmul_rn(dx, dx), __fmul_rn(dy, dy));
            if (m0 <= 0.0f || j0 == i) d0 = BIGD;
        }
        {
            const float2 c1 = *(const float2*)(xb + j1 * XCH);
            const float m1 = xb[j1 * XCH + (XCH - 1)];
            float dx = cix - c1.x, dy = ciy - c1.y;
            d1 = __fadd_rn(__fmul_rn(dx, dx), __fmul_rn(dy, dy));
            if (m1 <= 0.0f || j1 == i) d1 = BIGD;
        }

        const unsigned d0b = __float_as_uint(d0);
        const unsigned d1b = __float_as_uint(d1);

        unsigned long long A0 = ~0ull, A1 = ~0ull, W0 = 0ull, W1 = 0ull;
        int need = KK;
        int asz = 2 * 64;   // |A|

        auto step = [&](unsigned long long q0, unsigned long long q1) {
            const unsigned long long z0 = A0 & q0;
            const unsigned long long z1 = A1 & q1;
            const int c = __popcll(z0) + __popcll(z1);
            if (c == need) { W0 |= z0; W1 |= z1; A0 = A1 = 0ull; need = 0; }
            else if (c > need) { A0 = z0; A1 = z1; asz = c; }
            else { W0 |= z0; W1 |= z1; need -= c; A0 &= ~z0; A1 &= ~z1; asz -= c; }
        };

        // phase A: radix-4 digits over d bits (30,29),(28,27),...,(2,1)
#pragma unroll 1
        for (int t = 14; t >= 0; --t) {
            const unsigned dg0 = (d0b >> (2 * t + 1)) & 3u;
            const unsigned dg1 = (d1b >> (2 * t + 1)) & 3u;
            const unsigned long long p0_0  = __ballot(dg0 == 0u);
            const unsigned long long p1_0  = __ballot(dg1 == 0u);
            const unsigned long long p0_01 = __ballot(dg0 <= 1u);
            const unsigned long long p1_01 = __ballot(dg1 <= 1u);
            const unsigned long long p0_02 = __ballot(dg0 <= 2u);
            const unsigned long long p1_02 = __ballot(dg1 <= 2u);
            const unsigned long long z0_0  = A0 & p0_0,  z1_0  = A1 & p1_0;
            const unsigned long long z0_01 = A0 & p0_01, z1_01 = A1 & p1_01;
            const unsigned long long z0_02 = A0 & p0_02, z1_02 = A1 & p1_02;
            const int c0  = __popcll(z0_0)  + __popcll(z1_0);
            const int c01 = __popcll(z0_01) + __popcll(z1_01);
            const int c02 = __popcll(z0_02) + __popcll(z1_02);
            if (c0 >= need) {
                A0 = z0_0; A1 = z1_0; asz = c0;
            } else if (c01 >= need) {
                W0 |= z0_0; W1 |= z1_0; need -= c0;
                A0 = z0_01 & ~p0_0; A1 = z1_01 & ~p1_0; asz = c01 - c0;
            } else if (c02 >= need) {
                W0 |= z0_01; W1 |= z1_01; need -= c01;
                A0 = z0_02 & ~p0_01; A1 = z1_02 & ~p1_01; asz = c02 - c01;
            } else {
                W0 |= z0_02; W1 |= z1_02; need -= c02;
                A0 &= ~p0_02; A1 &= ~p1_02; asz -= c02;
            }
            if (asz == need) { W0 |= A0; W1 |= A1; A0 = A1 = 0ull; need = 0; break; }
        }
        // phase A': last d bit (bit 0)
        if (need) {
            const unsigned long long q0 = __ballot((d0b & 1u) == 0u);
            const unsigned long long q1 = __ballot((d1b & 1u) == 0u);
            step(q0, q1);
        }
        // phase B: index bits 6..0 (j0 = lane, j1 = lane+64): constant masks
        if (need) step(~0ull, 0ull);  // bit 6: all j0 are 0, all j1 are 1
        {
            const unsigned long long M5 = 0x00000000FFFFFFFFull;
            const unsigned long long M4 = 0x0000FFFF0000FFFFull;
            const unsigned long long M3 = 0x00FF00FF00FF00FFull;
            const unsigned long long M2 = 0x0F0F0F0F0F0F0F0Full;
            const unsigned long long M1 = 0x3333333333333333ull;
            const unsigned long long M0 = 0x5555555555555555ull;
            if (need) step(M5, M5);
            if (need) step(M4, M4);
            if (need) step(M3, M3);
            if (need) step(M2, M2);
            if (need) step(M1, M1);
            if (need) step(M0, M0);
        }
        W0 |= A0; W1 |= A1;  // keys unique => remaining actives = the rest

        unsigned int mb0 = __builtin_amdgcn_mbcnt_lo((unsigned)(W0 & 0xffffffffull), 0u);
        mb0 = __builtin_amdgcn_mbcnt_hi((unsigned)(W0 >> 32), mb0);
        unsigned int mb1 = __builtin_amdgcn_mbcnt_lo((unsigned)(W1 & 0xffffffffull), 0u);
        mb1 = __builtin_amdgcn_mbcnt_hi((unsigned)(W1 >> 32), mb1);
        const int base1 = __popcll(W0);

        if ((W0 >> lane) & 1ull) sknn[w][mb0] = j0;
        if ((W1 >> lane) & 1ull) sknn[w][base1 + mb1] = j1;
    } else {
        if (lane < KK) sknn[w][lane] = 0;  // dummy valid indices (row masked to 0)
    }
    // NO barrier: wave w reads only its own sknn[w] (lgkmcnt-ordered)

    // ================= edge build -> GEMM1 B-fragment (registers only) =====
    // this thread: point g=w, neighbor slot lcol, channel block quad (8 ch)
    const int jn = sknn[w][lcol];
    const float* ci = xb + i * XCH;
    const float* cj = xb + jn * XCH;
    // rows are 40 B apart -> 8 B aligned: use float2 loads
    const float2 a01 = *(const float2*)(ci + 0);
    const float2 a23 = *(const float2*)(ci + 2);
    const float2 a45 = *(const float2*)(ci + 4);
    const float2 a67 = *(const float2*)(ci + 6);
    const float  a8  = ci[8];
    const float2 n01 = *(const float2*)(cj + 0);
    const float2 n23 = *(const float2*)(cj + 2);
    const float2 n45 = *(const float2*)(cj + 4);
    const float2 n67 = *(const float2*)(cj + 6);
    const float  n8  = cj[8];

    float v[8];
#pragma unroll
    for (int e = 0; e < 8; ++e) v[e] = 0.0f;
    if (quad == 0) {           // channels 0..7 = center ch 0..7
        v[0] = a01.x; v[1] = a01.y; v[2] = a23.x; v[3] = a23.y;
        v[4] = a45.x; v[5] = a45.y; v[6] = a67.x; v[7] = a67.y;
    } else if (quad == 1) {    // ch 8 = center ch8; ch 9..15 = diff ch 0..6
        v[0] = a8;
        v[1] = n01.x - a01.x; v[2] = n01.y - a01.y;
        v[3] = n23.x - a23.x; v[4] = n23.y - a23.y;
        v[5] = n45.x - a45.x; v[6] = n45.y - a45.y;
        v[7] = n67.x - a67.x;
    } else if (quad == 2) {    // ch 16 = diff ch7; ch 17 = diff ch8; rest 0
        v[0] = n67.y - a67.y;
        v[1] = n8 - a8;
    }                          // quad 3: zero padding (K 18 -> 32)

    bf16x8 ef;
#pragma unroll
    for (int e = 0; e < 8; ++e) ef[e] = (__bf16)v[e];

    // ---- GEMM1 (MFMA): h1^T tiles; A = W1p frags (global/L1), B = ef ----
    bf16x8 wf[8];
#pragma unroll
    for (int nt = 0; nt < 8; ++nt)
        wf[nt] = *(const bf16x8*)&W1p[(size_t)((nt * 64 + lane) * 8)];

    const f32x4 z4 = {0.0f, 0.0f, 0.0f, 0.0f};
    f32x4 h[8];
#pragma unroll
    for (int nt = 0; nt < 8; ++nt)
        h[nt] = __builtin_amdgcn_mfma_f32_16x16x32_bf16(wf[nt], ef, z4, 0, 0, 0);

    // ---- epilogue 1: relu(+b1), write bf16 into GEMM2 A-frag order ----
    // C layout: col = lcol = edge row (within tile w), row = quad*4+r = h1
    // feature m = GEMM2's k. 4 consecutive k per (nt,quad) -> one b64 write.
#pragma unroll
    for (int nt = 0; nt < 8; ++nt) {
        const int ks = nt >> 1;
        const int lp = (((nt * 2 + (quad >> 1)) & 3) << 4) | lcol;
        bf16x4 hv;
#pragma unroll
        for (int r = 0; r < 4; ++r) {
            const int m = nt * 16 + quad * 4 + r;
            hv[r] = (__bf16)fmaxf(h[nt][r] + sb1[m], 0.0f);
        }
        *(bf16x4*)&sh1A[((ks * GPT + w) * 64 + lp) * 8 + (quad & 1) * 4] = hv;
    }
    __syncthreads();

    // ---- GEMM2 (MFMA): h2[64][256] = relu(h1 @ W2 + b2), fused K-mean ----
    f32x4 acc[GPT][4];
#pragma unroll
    for (int g = 0; g < GPT; ++g)
#pragma unroll
        for (int ct = 0; ct < 4; ++ct) acc[g][ct] = z4;

#pragma unroll
    for (int ks = 0; ks < 4; ++ks) {
        bf16x8 af[GPT], bfr[4];
#pragma unroll
        for (int g = 0; g < GPT; ++g)
            af[g] = *(const bf16x8*)&sh1A[((ks * GPT + g) * 64 + lane) * 8];
#pragma unroll
        for (int ct = 0; ct < 4; ++ct)
            bfr[ct] = *(const bf16x8*)&W2p[(size_t)((((w * 4 + ct) * 4 + ks) * 64 + lane) * 8)];
#pragma unroll
        for (int g = 0; g < GPT; ++g)
#pragma unroll
            for (int ct = 0; ct < 4; ++ct)
                acc[g][ct] = __builtin_amdgcn_mfma_f32_16x16x32_bf16(
                    af[g], bfr[ct], acc[g][ct], 0, 0, 0);
    }

    // ---- epilogue 2: relu(+b2), K-sum = tile column sum via shuffles ----
    // C layout: col=lcol, row=quad*4+r; tile g's 16 rows = point g's K
    // neighbors. Partial over 4 rows in-lane, then fold quads (xor 16, 32).
    float val[4];
#pragma unroll
    for (int g = 0; g < GPT; ++g) {
#pragma unroll
        for (int ct = 0; ct < 4; ++ct) {
            const int col = w * 64 + ct * 16 + lcol;
            const float bc = sb2[col];
            float s = 0.0f;
#pragma unroll
            for (int r = 0; r < 4; ++r) s += fmaxf(acc[g][ct][r] + bc, 0.0f);
            s += __shfl_xor(s, 16, 64);
            s += __shfl_xor(s, 32, 64);
            if (quad == g) val[ct] = s;   // lane (quad=g, lcol) keeps point g
        }
    }
    const float m = smask[quad] * (1.0f / KK);
#pragma unroll
    for (int ct = 0; ct < 4; ++ct)
        outrow[(size_t)quad * (OO + 1) + w * 64 + ct * 16 + lcol] = val[ct] * m;
    if (tid < GPT) outrow[(size_t)tid * (OO + 1) + OO] = smask[tid];  // ones ch * mask
}

extern "C" void kernel_launch(void* const* d_in, const int* in_sizes, int n_in,
                              void* d_out, int out_size, void* d_ws, size_t ws_size,
                              hipStream_t stream) {
    const float* x  = (const float*)d_in[0];
    const float* W1 = (const float*)d_in[1];
    const float* b1 = (const float*)d_in[2];
    const float* W2 = (const float*)d_in[3];
    const float* b2 = (const float*)d_in[4];
    float* out = (float*)d_out;

    __bf16* W2p = (__bf16*)d_ws;                    // 64 KB
    __bf16* W1p = (__bf16*)((char*)d_ws + 65536);   // 8 KB

    pack_w_kernel<<<144, 256, 0, stream>>>(W1, W2, W2p, W1p);

    const int nblocks = (BB * PP) / GPT;  // 8192
    mlp_kernel<<<nblocks, 256, 0, stream>>>(x, W1p, b1, W2p, b2, out);
}